// Round 3
// baseline (3180.060 us; speedup 1.0000x reference)
//
#include <hip/hip_runtime.h>
#include <hip/hip_bf16.h>
#include <math.h>

// Problem constants (Qwen3Attention): T=2048, HID=2048, H=16, KV=8, D=128
#define T_TOK 2048
#define HID 2048
#define NH 16
#define NKV 8
#define HD 128
#define QKV_N (NH*HD + 2*NKV*HD)   // 4096
#define EPS 1e-6f
#define THETA 1.0e6f

// ---------------------------------------------------------------------------
// Tiled fp32 GEMM, C[M,N] = A[M,K] * B[N,K]^T
// A row-major MxK with row stride lda; B row-major NxK (ldb=K); C row stride N.
// 64x64 block tile, BK=16, 256 threads, 4x4 microtile per thread.
// ---------------------------------------------------------------------------
__global__ __launch_bounds__(256) void gemm_nt_f32(
    const float* __restrict__ A, const float* __restrict__ B,
    float* __restrict__ C, int M, int N, int K, int lda)
{
    __shared__ float As[16][68];   // [k][m]
    __shared__ float Bs[16][68];   // [k][n]

    const int tid = threadIdx.x;          // 0..255
    const int m0  = blockIdx.y * 64;
    const int n0  = blockIdx.x * 64;
    const int lr  = tid >> 2;             // 0..63 : tile row for loads
    const int lk  = (tid & 3) << 2;       // 0,4,8,12 : k offset for loads
    const int tm  = tid >> 4;             // 0..15
    const int tn  = tid & 15;             // 0..15

    float acc[4][4];
    #pragma unroll
    for (int i = 0; i < 4; ++i)
        #pragma unroll
        for (int j = 0; j < 4; ++j) acc[i][j] = 0.f;

    for (int k0 = 0; k0 < K; k0 += 16) {
        float4 a = *(const float4*)(A + (size_t)(m0 + lr) * lda + k0 + lk);
        float4 b = *(const float4*)(B + (size_t)(n0 + lr) * K   + k0 + lk);
        __syncthreads();   // previous iteration's LDS reads must finish
        As[lk+0][lr] = a.x; As[lk+1][lr] = a.y; As[lk+2][lr] = a.z; As[lk+3][lr] = a.w;
        Bs[lk+0][lr] = b.x; Bs[lk+1][lr] = b.y; Bs[lk+2][lr] = b.z; Bs[lk+3][lr] = b.w;
        __syncthreads();
        #pragma unroll
        for (int kk = 0; kk < 16; ++kk) {
            float av[4], bv[4];
            #pragma unroll
            for (int i = 0; i < 4; ++i) av[i] = As[kk][tm*4 + i];
            #pragma unroll
            for (int j = 0; j < 4; ++j) bv[j] = Bs[kk][tn*4 + j];
            #pragma unroll
            for (int i = 0; i < 4; ++i)
                #pragma unroll
                for (int j = 0; j < 4; ++j)
                    acc[i][j] = fmaf(av[i], bv[j], acc[i][j]);
        }
    }

    #pragma unroll
    for (int i = 0; i < 4; ++i) {
        float4 o = make_float4(acc[i][0], acc[i][1], acc[i][2], acc[i][3]);
        *(float4*)(C + (size_t)(m0 + tm*4 + i) * N + n0 + tn*4) = o;
    }
}

// ---------------------------------------------------------------------------
// RMSNorm + RoPE, in-place on the qkv buffer.
// grid = (T, NH+NKV), block = 128 threads (one per dim element).
// ---------------------------------------------------------------------------
__global__ __launch_bounds__(128) void norm_rope(
    float* __restrict__ qkv, const int* __restrict__ positions,
    const float* __restrict__ qw, const float* __restrict__ kw)
{
    const int t   = blockIdx.x;
    const int hh  = blockIdx.y;
    const int tid = threadIdx.x;

    float* p; const float* w;
    if (hh < NH) { p = qkv + (size_t)t*QKV_N + hh*HD;              w = qw; }
    else         { p = qkv + (size_t)t*QKV_N + NH*HD + (hh-NH)*HD; w = kw; }

    float x = p[tid];

    __shared__ float red[2];
    float ss = x * x;
    #pragma unroll
    for (int o = 32; o > 0; o >>= 1) ss += __shfl_down(ss, o);
    if ((tid & 63) == 0) red[tid >> 6] = ss;
    __syncthreads();
    const float var = (red[0] + red[1]) * (1.0f / (float)HD);
    float xn = x * rsqrtf(var + EPS) * w[tid];

    __shared__ float sx[HD];
    sx[tid] = xn;
    __syncthreads();

    const int   pos = positions[t];
    const int   i   = tid & 63;                       // rotary pair index
    // inv_freq = THETA^(-i/64) = exp2(-i * log2(THETA)/64)
    const float inv_freq = exp2f(-(float)i * 0.311430758895690f /* log2(1e6)/64 */);
    const float ang = (float)pos * inv_freq;
    // NOTE: sincosf's pointer order is (sin, cos) — round-1/2 bug had them
    // swapped, negating the relative RoPE angle. Use explicit calls.
    const float s = sinf(ang);
    const float c = cosf(ang);

    float out;
    if (tid < 64) out = sx[i]      * c - sx[i + 64] * s;
    else          out = sx[i + 64] * c + sx[i]      * s;
    p[tid] = out;
}

// ---------------------------------------------------------------------------
// Causal GQA attention, fp32. grid = (T, NH), block = 128.
// Output written IN-PLACE into the q slot of qkv (safe: only this block ever
// reads q[t,h,:], and it snapshots it to LDS before any write).
// ---------------------------------------------------------------------------
__global__ __launch_bounds__(128) void attn(float* __restrict__ qkv)
{
    const int t   = blockIdx.x;
    const int h   = blockIdx.y;
    const int kvh = h >> 1;               // rep = H/KV = 2
    const int tid = threadIdx.x;

    __shared__ float sq[HD];
    __shared__ float sc[T_TOK];
    __shared__ float redm[2];
    __shared__ float reds[2];

    sq[tid] = qkv[(size_t)t*QKV_N + h*HD + tid];
    __syncthreads();

    const float scale = 0.08838834764831845f;  // 1/sqrt(128)
    const float* kbase = qkv + NH*HD + (size_t)kvh*HD;

    // phase 1: scores (each thread owns s = tid, tid+128, ...)
    for (int s = tid; s <= t; s += 128) {
        const float4* kp = (const float4*)(kbase + (size_t)s*QKV_N);
        const float4* qp = (const float4*)sq;
        float d = 0.f;
        #pragma unroll 8
        for (int i = 0; i < HD/4; ++i) {
            float4 k4 = kp[i], q4 = qp[i];
            d += q4.x*k4.x + q4.y*k4.y + q4.z*k4.z + q4.w*k4.w;
        }
        sc[s] = d * scale;
    }

    // phase 2: softmax (each thread touches only its own s values)
    float lm = -1e30f;
    for (int s = tid; s <= t; s += 128) lm = fmaxf(lm, sc[s]);
    #pragma unroll
    for (int oo = 32; oo > 0; oo >>= 1) lm = fmaxf(lm, __shfl_down(lm, oo));
    if ((tid & 63) == 0) redm[tid >> 6] = lm;
    __syncthreads();
    const float m = fmaxf(redm[0], redm[1]);

    float ls = 0.f;
    for (int s = tid; s <= t; s += 128) {
        float e = __expf(sc[s] - m);
        sc[s] = e;
        ls += e;
    }
    #pragma unroll
    for (int oo = 32; oo > 0; oo >>= 1) ls += __shfl_down(ls, oo);
    if ((tid & 63) == 0) reds[tid >> 6] = ls;
    __syncthreads();
    const float inv_l = 1.0f / (reds[0] + reds[1]);
    __syncthreads();   // all sc[] writes visible before cross-thread reads

    // phase 3: o[t,h,d] = sum_s p[s] * v[s,kvh,d], d = tid (coalesced)
    const float* vb = qkv + (NH*HD + NKV*HD) + (size_t)kvh*HD + tid;
    float acc = 0.f;
    for (int s = 0; s <= t; ++s)
        acc = fmaf(sc[s], vb[(size_t)s*QKV_N], acc);

    // in-place: overwrite this block's own q slot with the attention output
    qkv[(size_t)t*QKV_N + h*HD + tid] = acc * inv_l;
}

// ---------------------------------------------------------------------------
extern "C" void kernel_launch(void* const* d_in, const int* in_sizes, int n_in,
                              void* d_out, int out_size, void* d_ws, size_t ws_size,
                              hipStream_t stream)
{
    const float* hidden    = (const float*)d_in[0];   // T x HID
    const int*   positions = (const int*)  d_in[1];   // T
    const float* qkv_w     = (const float*)d_in[2];   // QKV_N x HID
    const float* o_w       = (const float*)d_in[3];   // HID x (NH*HD)
    const float* q_norm_w  = (const float*)d_in[4];   // HD
    const float* k_norm_w  = (const float*)d_in[5];   // HD
    float* out = (float*)d_out;                       // T x HID

    // workspace: qkv only (T x 4096 f32 = 32 MB). Attention output goes
    // in-place into the q section, so no second buffer is needed.
    float* qkv = (float*)d_ws;

    // 1) qkv = hidden @ qkv_w^T   (M=2048, N=4096, K=2048)
    {
        dim3 grid(QKV_N / 64, T_TOK / 64);
        gemm_nt_f32<<<grid, 256, 0, stream>>>(hidden, qkv_w, qkv, T_TOK, QKV_N, HID, HID);
    }
    // 2) rmsnorm + rope on q and k heads, in place
    {
        dim3 grid(T_TOK, NH + NKV);
        norm_rope<<<grid, 128, 0, stream>>>(qkv, positions, q_norm_w, k_norm_w);
    }
    // 3) causal GQA attention -> q section of qkv (in place)
    {
        dim3 grid(T_TOK, NH);
        attn<<<grid, 128, 0, stream>>>(qkv);
    }
    // 4) out = o @ o_w^T   (M=2048, N=2048, K=2048), A = qkv rows, lda=4096
    {
        dim3 grid(HID / 64, T_TOK / 64);
        gemm_nt_f32<<<grid, 256, 0, stream>>>(qkv, o_w, out, T_TOK, HID, HID, QKV_N);
    }
}

// Round 4
// 1627.658 us; speedup vs baseline: 1.9538x; 1.9538x over previous
//
#include <hip/hip_runtime.h>
#include <hip/hip_bf16.h>
#include <math.h>

// Problem constants (Qwen3Attention): T=2048, HID=2048, H=16, KV=8, D=128
#define T_TOK 2048
#define HID 2048
#define NH 16
#define NKV 8
#define HD 128
#define QKV_N (NH*HD + 2*NKV*HD)   // 4096
#define EPS 1e-6f
#define THETA 1.0e6f

// ---------------------------------------------------------------------------
// Tiled fp32 GEMM, C[M,N] = A[M,K] * B[N,K]^T
// ---------------------------------------------------------------------------
__global__ __launch_bounds__(256) void gemm_nt_f32(
    const float* __restrict__ A, const float* __restrict__ B,
    float* __restrict__ C, int M, int N, int K, int lda)
{
    __shared__ float As[16][68];   // [k][m]
    __shared__ float Bs[16][68];   // [k][n]

    const int tid = threadIdx.x;          // 0..255
    const int m0  = blockIdx.y * 64;
    const int n0  = blockIdx.x * 64;
    const int lr  = tid >> 2;             // 0..63
    const int lk  = (tid & 3) << 2;       // 0,4,8,12
    const int tm  = tid >> 4;             // 0..15
    const int tn  = tid & 15;             // 0..15

    float acc[4][4];
    #pragma unroll
    for (int i = 0; i < 4; ++i)
        #pragma unroll
        for (int j = 0; j < 4; ++j) acc[i][j] = 0.f;

    for (int k0 = 0; k0 < K; k0 += 16) {
        float4 a = *(const float4*)(A + (size_t)(m0 + lr) * lda + k0 + lk);
        float4 b = *(const float4*)(B + (size_t)(n0 + lr) * K   + k0 + lk);
        __syncthreads();
        As[lk+0][lr] = a.x; As[lk+1][lr] = a.y; As[lk+2][lr] = a.z; As[lk+3][lr] = a.w;
        Bs[lk+0][lr] = b.x; Bs[lk+1][lr] = b.y; Bs[lk+2][lr] = b.z; Bs[lk+3][lr] = b.w;
        __syncthreads();
        #pragma unroll
        for (int kk = 0; kk < 16; ++kk) {
            float av[4], bv[4];
            #pragma unroll
            for (int i = 0; i < 4; ++i) av[i] = As[kk][tm*4 + i];
            #pragma unroll
            for (int j = 0; j < 4; ++j) bv[j] = Bs[kk][tn*4 + j];
            #pragma unroll
            for (int i = 0; i < 4; ++i)
                #pragma unroll
                for (int j = 0; j < 4; ++j)
                    acc[i][j] = fmaf(av[i], bv[j], acc[i][j]);
        }
    }

    #pragma unroll
    for (int i = 0; i < 4; ++i) {
        float4 o = make_float4(acc[i][0], acc[i][1], acc[i][2], acc[i][3]);
        *(float4*)(C + (size_t)(m0 + tm*4 + i) * N + n0 + tn*4) = o;
    }
}

// ---------------------------------------------------------------------------
// RMSNorm + RoPE, in-place on the qkv buffer.
// ---------------------------------------------------------------------------
__global__ __launch_bounds__(128) void norm_rope(
    float* __restrict__ qkv, const int* __restrict__ positions,
    const float* __restrict__ qw, const float* __restrict__ kw)
{
    const int t   = blockIdx.x;
    const int hh  = blockIdx.y;
    const int tid = threadIdx.x;

    float* p; const float* w;
    if (hh < NH) { p = qkv + (size_t)t*QKV_N + hh*HD;              w = qw; }
    else         { p = qkv + (size_t)t*QKV_N + NH*HD + (hh-NH)*HD; w = kw; }

    float x = p[tid];

    __shared__ float red[2];
    float ss = x * x;
    #pragma unroll
    for (int o = 32; o > 0; o >>= 1) ss += __shfl_down(ss, o);
    if ((tid & 63) == 0) red[tid >> 6] = ss;
    __syncthreads();
    const float var = (red[0] + red[1]) * (1.0f / (float)HD);
    float xn = x * rsqrtf(var + EPS) * w[tid];

    __shared__ float sx[HD];
    sx[tid] = xn;
    __syncthreads();

    const int   pos = positions[t];
    const int   i   = tid & 63;
    const float inv_freq = exp2f(-(float)i * 0.311430758895690f /* log2(1e6)/64 */);
    const float ang = (float)pos * inv_freq;
    const float s = sinf(ang);
    const float c = cosf(ang);

    float out;
    if (tid < 64) out = sx[i]      * c - sx[i + 64] * s;
    else          out = sx[i + 64] * c + sx[i]      * s;
    p[tid] = out;
}

// ---------------------------------------------------------------------------
// Flash-style causal GQA attention, fp32, LDS-tiled.
// grid = (T/64, NH); block = 256 threads (16x16 thread grid).
// Q-tile: 64 rows x 128. s-tiles of 32 staged in LDS. Online softmax.
// Output written in-place into the q slots of qkv.
// Thread (tm,tn): S microtile rows tm*4+{0..3}, cols tn*2+{0..1};
//                 O microtile rows tm*4+{0..3}, cols tn*8+{0..7}.
// ---------------------------------------------------------------------------
#define QT 64
#define ST 32
#define LDQ 132
#define LDK 132
#define LDP 33

__global__ __launch_bounds__(256) void attn_flash(float* __restrict__ qkv)
{
    const int qt  = (int)(gridDim.x - 1) - (int)blockIdx.x;  // heavy tiles first
    const int h   = blockIdx.y;
    const int kvh = h >> 1;               // rep = H/KV = 2
    const int t0  = qt * QT;
    const int tid = threadIdx.x;
    const int tm  = tid >> 4;             // 0..15
    const int tn  = tid & 15;             // 0..15

    __shared__ float Qs[QT][LDQ];         // 33792 B
    __shared__ float KVs[ST][LDK];        // 16896 B (K then V per tile)
    __shared__ float Ps[QT][LDP];         //  8448 B   -> 59136 B total

    const float scale = 0.08838834764831845f;  // 1/sqrt(128)

    // ---- stage Q tile (pre-scaled) ----
    {
        const int r  = tid >> 5;          // 0..7
        const int c4 = (tid & 31) * 4;    // 0..124
        #pragma unroll
        for (int p = 0; p < 8; ++p) {
            const int row = r + p * 8;
            float4 v = *(const float4*)(qkv + (size_t)(t0 + row) * QKV_N + h * HD + c4);
            Qs[row][c4+0] = v.x * scale;
            Qs[row][c4+1] = v.y * scale;
            Qs[row][c4+2] = v.z * scale;
            Qs[row][c4+3] = v.w * scale;
        }
    }

    float m_run[4], l_part[4], Oa[4][8];
    #pragma unroll
    for (int i = 0; i < 4; ++i) {
        m_run[i] = -3.0e38f;
        l_part[i] = 0.f;
        #pragma unroll
        for (int k = 0; k < 8; ++k) Oa[i][k] = 0.f;
    }

    const float* kglob = qkv + NH*HD           + (size_t)kvh*HD;
    const float* vglob = qkv + NH*HD + NKV*HD  + (size_t)kvh*HD;

    const int ntiles = (t0 >> 5) + 2;     // s0 up to t0+32 (covers cols <= t0+63)

    for (int tile = 0; tile < ntiles; ++tile) {
        const int s0 = tile * ST;

        __syncthreads();   // prev PV reads of KVs done; Q staged (iter 0)
        // ---- stage K tile ----
        {
            const int r  = tid >> 5;
            const int c4 = (tid & 31) * 4;
            #pragma unroll
            for (int p = 0; p < 4; ++p) {
                const int row = r + p * 8;
                float4 v = *(const float4*)(kglob + (size_t)(s0 + row) * QKV_N + c4);
                KVs[row][c4+0] = v.x; KVs[row][c4+1] = v.y;
                KVs[row][c4+2] = v.z; KVs[row][c4+3] = v.w;
            }
        }
        __syncthreads();

        // ---- S = Q K^T (4x2 per thread) ----
        float s_acc[4][2];
        #pragma unroll
        for (int i = 0; i < 4; ++i) { s_acc[i][0] = 0.f; s_acc[i][1] = 0.f; }
        for (int d = 0; d < HD; d += 4) {
            float4 k0 = *(const float4*)&KVs[tn*2+0][d];
            float4 k1 = *(const float4*)&KVs[tn*2+1][d];
            #pragma unroll
            for (int i = 0; i < 4; ++i) {
                float4 q = *(const float4*)&Qs[tm*4+i][d];
                s_acc[i][0] += q.x*k0.x + q.y*k0.y + q.z*k0.z + q.w*k0.w;
                s_acc[i][1] += q.x*k1.x + q.y*k1.y + q.z*k1.z + q.w*k1.w;
            }
        }

        // ---- causal mask (only tiles that touch the diagonal) ----
        if (s0 + ST - 1 > t0) {
            #pragma unroll
            for (int i = 0; i < 4; ++i) {
                const int t = t0 + tm*4 + i;
                #pragma unroll
                for (int j = 0; j < 2; ++j) {
                    const int s = s0 + tn*2 + j;
                    if (s > t) s_acc[i][j] = -1.0e30f;
                }
            }
        }

        // ---- online softmax update ----
        float mt[4];
        #pragma unroll
        for (int i = 0; i < 4; ++i) mt[i] = fmaxf(s_acc[i][0], s_acc[i][1]);
        #pragma unroll
        for (int x = 1; x < 16; x <<= 1)
            #pragma unroll
            for (int i = 0; i < 4; ++i)
                mt[i] = fmaxf(mt[i], __shfl_xor(mt[i], x));

        #pragma unroll
        for (int i = 0; i < 4; ++i) {
            const float mn = fmaxf(m_run[i], mt[i]);
            const float al = __expf(m_run[i] - mn);   // 0 on first tile
            m_run[i] = mn;
            const float p0 = __expf(s_acc[i][0] - mn);
            const float p1 = __expf(s_acc[i][1] - mn);
            l_part[i] = l_part[i] * al + p0 + p1;
            #pragma unroll
            for (int k = 0; k < 8; ++k) Oa[i][k] *= al;
            Ps[tm*4+i][tn*2+0] = p0;
            Ps[tm*4+i][tn*2+1] = p1;
        }
        __syncthreads();   // P visible; all K reads done

        // ---- stage V tile (overwrites KVs) ----
        {
            const int r  = tid >> 5;
            const int c4 = (tid & 31) * 4;
            #pragma unroll
            for (int p = 0; p < 4; ++p) {
                const int row = r + p * 8;
                float4 v = *(const float4*)(vglob + (size_t)(s0 + row) * QKV_N + c4);
                KVs[row][c4+0] = v.x; KVs[row][c4+1] = v.y;
                KVs[row][c4+2] = v.z; KVs[row][c4+3] = v.w;
            }
        }
        __syncthreads();

        // ---- O += P V ----
        for (int j = 0; j < ST; ++j) {
            float4 v0 = *(const float4*)&KVs[j][tn*8];
            float4 v1 = *(const float4*)&KVs[j][tn*8+4];
            #pragma unroll
            for (int i = 0; i < 4; ++i) {
                const float p = Ps[tm*4+i][j];
                Oa[i][0] += p*v0.x; Oa[i][1] += p*v0.y;
                Oa[i][2] += p*v0.z; Oa[i][3] += p*v0.w;
                Oa[i][4] += p*v1.x; Oa[i][5] += p*v1.y;
                Oa[i][6] += p*v1.z; Oa[i][7] += p*v1.w;
            }
        }
    }

    // ---- finalize: reduce l across the 16-thread row group, write out ----
    #pragma unroll
    for (int x = 1; x < 16; x <<= 1)
        #pragma unroll
        for (int i = 0; i < 4; ++i)
            l_part[i] += __shfl_xor(l_part[i], x);

    #pragma unroll
    for (int i = 0; i < 4; ++i) {
        const float inv = 1.0f / l_part[i];
        float* op = qkv + (size_t)(t0 + tm*4 + i) * QKV_N + h * HD + tn*8;
        float4 o0 = make_float4(Oa[i][0]*inv, Oa[i][1]*inv, Oa[i][2]*inv, Oa[i][3]*inv);
        float4 o1 = make_float4(Oa[i][4]*inv, Oa[i][5]*inv, Oa[i][6]*inv, Oa[i][7]*inv);
        *(float4*)(op)     = o0;
        *(float4*)(op + 4) = o1;
    }
}

// ---------------------------------------------------------------------------
extern "C" void kernel_launch(void* const* d_in, const int* in_sizes, int n_in,
                              void* d_out, int out_size, void* d_ws, size_t ws_size,
                              hipStream_t stream)
{
    const float* hidden    = (const float*)d_in[0];   // T x HID
    const int*   positions = (const int*)  d_in[1];   // T
    const float* qkv_w     = (const float*)d_in[2];   // QKV_N x HID
    const float* o_w       = (const float*)d_in[3];   // HID x (NH*HD)
    const float* q_norm_w  = (const float*)d_in[4];   // HD
    const float* k_norm_w  = (const float*)d_in[5];   // HD
    float* out = (float*)d_out;                       // T x HID

    float* qkv = (float*)d_ws;   // 32 MB: T x 4096 f32; attn out goes in-place

    // 1) qkv = hidden @ qkv_w^T
    {
        dim3 grid(QKV_N / 64, T_TOK / 64);
        gemm_nt_f32<<<grid, 256, 0, stream>>>(hidden, qkv_w, qkv, T_TOK, QKV_N, HID, HID);
    }
    // 2) rmsnorm + rope
    {
        dim3 grid(T_TOK, NH + NKV);
        norm_rope<<<grid, 128, 0, stream>>>(qkv, positions, q_norm_w, k_norm_w);
    }
    // 3) flash attention (in place into q slots)
    {
        dim3 grid(T_TOK / QT, NH);
        attn_flash<<<grid, 256, 0, stream>>>(qkv);
    }
    // 4) out = o @ o_w^T
    {
        dim3 grid(HID / 64, T_TOK / 64);
        gemm_nt_f32<<<grid, 256, 0, stream>>>(qkv, o_w, out, T_TOK, HID, HID, QKV_N);
    }
}

// Round 5
// 961.355 us; speedup vs baseline: 3.3079x; 1.6931x over previous
//
#include <hip/hip_runtime.h>
#include <math.h>

// Qwen3Attention: T=2048, HID=2048, H=16, KV=8, D=128
#define T_TOK 2048
#define HID 2048
#define NH 16
#define NKV 8
#define HD 128
#define QKV_N 4096
#define EPS 1e-6f

typedef unsigned short u16;
typedef unsigned int   u32;
typedef __attribute__((ext_vector_type(8))) u16   u16x8;
typedef __attribute__((ext_vector_type(8))) short short8;
typedef __attribute__((ext_vector_type(4))) float floatx4;

__device__ __forceinline__ u16 f2bf(float x) {           // RNE f32->bf16
    u32 u = __float_as_uint(x);
    u = (u + 0x7fffu + ((u >> 16) & 1u)) >> 16;
    return (u16)u;
}
__device__ __forceinline__ float bf2f(u16 h) {
    return __uint_as_float(((u32)h) << 16);
}

// ---------------------------------------------------------------------------
// f32 -> bf16 elementwise (8 elems/thread). n must be a multiple of 2048.
// ---------------------------------------------------------------------------
__global__ __launch_bounds__(256) void cvt_f32_bf16(
    const float* __restrict__ in, u16* __restrict__ out)
{
    const size_t i = ((size_t)blockIdx.x * 256 + threadIdx.x) * 8;
    float4 a = *(const float4*)(in + i);
    float4 b = *(const float4*)(in + i + 4);
    u16x8 o;
    o[0] = f2bf(a.x); o[1] = f2bf(a.y); o[2] = f2bf(a.z); o[3] = f2bf(a.w);
    o[4] = f2bf(b.x); o[5] = f2bf(b.y); o[6] = f2bf(b.z); o[7] = f2bf(b.w);
    *(u16x8*)(out + i) = o;
}

// ---------------------------------------------------------------------------
// bf16 MFMA GEMM (m97 pattern): C[M,N] = A[M,K]*B[N,K]^T
// A: bf16 row-major stride lda; B: bf16 row-major stride ldb.
// 128x128 tile, BK=32, 256 thr (4 waves, each 64x64 = 4x4 of 16x16x32 MFMA).
// Staging via global_load_lds width=16 (wave-uniform base + lane*16).
// ---------------------------------------------------------------------------
template<bool OUT_BF16>
__global__ __launch_bounds__(256) void gemm_bt_bf16(
    const u16* __restrict__ A, const u16* __restrict__ B,
    void* __restrict__ Cv, int K, int lda, int ldb, int ldc)
{
    __shared__ short As[128 * 32];   // 8 KB, row-major [m][k], 64 B rows
    __shared__ short Bs[128 * 32];   // 8 KB, row-major [n][k]

    const int tid = threadIdx.x;
    const int w   = tid >> 6;             // wave 0..3
    const int l   = tid & 63;
    const int m0  = blockIdx.y * 128;
    const int n0  = blockIdx.x * 128;
    const int wm  = (w >> 1) * 64;
    const int wn  = (w & 1) * 64;
    const int lm  = l & 15;
    const int ko8 = (l >> 4) * 8;         // k-octet for A/B fragments

    // staging: thread -> row tid>>2 (4 thr/row, 8 elems each), issues 0/1 cover rows 0..63/64..127
    const u16* gA0 = A + (size_t)(m0      + (tid >> 2)) * lda + (tid & 3) * 8;
    const u16* gA1 = A + (size_t)(m0 + 64 + (tid >> 2)) * lda + (tid & 3) * 8;
    const u16* gB0 = B + (size_t)(n0      + (tid >> 2)) * ldb + (tid & 3) * 8;
    const u16* gB1 = B + (size_t)(n0 + 64 + (tid >> 2)) * ldb + (tid & 3) * 8;
    // wave-uniform LDS bases (HW scatters lane i at base + i*16 bytes)
    short* lA0 = As + w * 512;            // w*1024 B
    short* lA1 = As + 2048 + w * 512;     // +4096 B
    short* lB0 = Bs + w * 512;
    short* lB1 = Bs + 2048 + w * 512;

    floatx4 acc[4][4];
    #pragma unroll
    for (int i = 0; i < 4; ++i)
        #pragma unroll
        for (int j = 0; j < 4; ++j) acc[i][j] = (floatx4){0.f, 0.f, 0.f, 0.f};

    for (int k0 = 0; k0 < K; k0 += 32) {
        __syncthreads();   // previous iteration's LDS reads complete
        __builtin_amdgcn_global_load_lds(
            (const __attribute__((address_space(1))) u32*)(gA0 + k0),
            (__attribute__((address_space(3))) u32*)lA0, 16, 0, 0);
        __builtin_amdgcn_global_load_lds(
            (const __attribute__((address_space(1))) u32*)(gA1 + k0),
            (__attribute__((address_space(3))) u32*)lA1, 16, 0, 0);
        __builtin_amdgcn_global_load_lds(
            (const __attribute__((address_space(1))) u32*)(gB0 + k0),
            (__attribute__((address_space(3))) u32*)lB0, 16, 0, 0);
        __builtin_amdgcn_global_load_lds(
            (const __attribute__((address_space(1))) u32*)(gB1 + k0),
            (__attribute__((address_space(3))) u32*)lB1, 16, 0, 0);
        __syncthreads();   // vmcnt(0) drained before barrier -> tiles visible

        short8 af[4], bfr[4];
        #pragma unroll
        for (int i = 0; i < 4; ++i)
            af[i] = *(const short8*)(As + (wm + i * 16 + lm) * 32 + ko8);
        #pragma unroll
        for (int j = 0; j < 4; ++j)
            bfr[j] = *(const short8*)(Bs + (wn + j * 16 + lm) * 32 + ko8);
        #pragma unroll
        for (int i = 0; i < 4; ++i)
            #pragma unroll
            for (int j = 0; j < 4; ++j)
                acc[i][j] = __builtin_amdgcn_mfma_f32_16x16x32_bf16(
                    af[i], bfr[j], acc[i][j], 0, 0, 0);
    }

    // epilogue: C/D layout col=lane&15, row=(lane>>4)*4+reg  [m89-verified]
    const int r0 = (l >> 4) * 4;
    #pragma unroll
    for (int i = 0; i < 4; ++i)
        #pragma unroll
        for (int j = 0; j < 4; ++j)
            #pragma unroll
            for (int r = 0; r < 4; ++r) {
                const int row = m0 + wm + i * 16 + r0 + r;
                const int col = n0 + wn + j * 16 + lm;
                if (OUT_BF16)
                    ((u16*)Cv)[(size_t)row * ldc + col] = f2bf(acc[i][j][r]);
                else
                    ((float*)Cv)[(size_t)row * ldc + col] = acc[i][j][r];
            }
}

// ---------------------------------------------------------------------------
// RMSNorm + RoPE, in-place on bf16 qkv. grid=(T, NH+NKV), 128 thr.
// ---------------------------------------------------------------------------
__global__ __launch_bounds__(128) void norm_rope(
    u16* __restrict__ qkv, const int* __restrict__ positions,
    const float* __restrict__ qw, const float* __restrict__ kw)
{
    const int t   = blockIdx.x;
    const int hh  = blockIdx.y;
    const int tid = threadIdx.x;

    u16* p; const float* w;
    if (hh < NH) { p = qkv + (size_t)t*QKV_N + hh*HD;              w = qw; }
    else         { p = qkv + (size_t)t*QKV_N + NH*HD + (hh-NH)*HD; w = kw; }

    float x = bf2f(p[tid]);

    __shared__ float red[2];
    float ss = x * x;
    #pragma unroll
    for (int o = 32; o > 0; o >>= 1) ss += __shfl_down(ss, o);
    if ((tid & 63) == 0) red[tid >> 6] = ss;
    __syncthreads();
    const float var = (red[0] + red[1]) * (1.0f / (float)HD);
    float xn = x * rsqrtf(var + EPS) * w[tid];

    __shared__ float sx[HD];
    sx[tid] = xn;
    __syncthreads();

    const int   pos = positions[t];
    const int   i   = tid & 63;
    const float inv_freq = exp2f(-(float)i * 0.311430758895690f); // log2(1e6)/64
    const float ang = (float)pos * inv_freq;
    const float s = sinf(ang);   // NOTE: sincosf ptr order bug in r1/r2
    const float c = cosf(ang);

    float out;
    if (tid < 64) out = sx[i]      * c - sx[i + 64] * s;
    else          out = sx[i + 64] * c + sx[i]      * s;
    p[tid] = f2bf(out);
}

// ---------------------------------------------------------------------------
// Flash causal GQA attention, fp32 compute over bf16 qkv.
// grid=(T/32, NH), 256 thr. QT=ST=32. LDS 38 KB -> 4 blocks/CU.
// Thread (tm,tn): S rows tm*2+{0,1}, cols {tn, tn+16}; O cols tn*8+{0..7}.
// Output bf16, in-place into q slot.
// ---------------------------------------------------------------------------
#define LDK 132
__global__ __launch_bounds__(256) void attn_flash(u16* __restrict__ qkv)
{
    const int qt  = (int)(gridDim.x - 1) - (int)blockIdx.x;  // heavy first
    const int h   = blockIdx.y;
    const int kvh = h >> 1;
    const int t0  = qt * 32;
    const int tid = threadIdx.x;
    const int tm  = tid >> 4;             // 0..15
    const int tn  = tid & 15;             // 0..15

    __shared__ float Qs[32][LDK];         // 16896 B
    __shared__ float KVs[32][LDK];        // 16896 B
    __shared__ float Ps[32][33];          //  4224 B -> 38016 total

    const float scale = 0.08838834764831845f;  // 1/sqrt(128)
    const int srow = tid >> 3;            // staging row 0..31
    const int scol = (tid & 7) * 16;      // staging col base

    // ---- stage Q (pre-scaled) ----
    {
        const u16* g = qkv + (size_t)(t0 + srow) * QKV_N + h * HD + scol;
        u16x8 a = *(const u16x8*)g;
        u16x8 b = *(const u16x8*)(g + 8);
        #pragma unroll
        for (int e = 0; e < 8; ++e) {
            Qs[srow][scol + e]     = bf2f(a[e]) * scale;
            Qs[srow][scol + 8 + e] = bf2f(b[e]) * scale;
        }
    }

    float m_run[2]  = {-3.0e38f, -3.0e38f};
    float l_part[2] = {0.f, 0.f};
    float Oa[2][8];
    #pragma unroll
    for (int i = 0; i < 2; ++i)
        #pragma unroll
        for (int k = 0; k < 8; ++k) Oa[i][k] = 0.f;

    const u16* kg = qkv + (size_t)NH*HD            + (size_t)kvh*HD;
    const u16* vg = qkv + (size_t)(NH*HD + NKV*HD) + (size_t)kvh*HD;

    const int ntiles = qt + 1;
    for (int tile = 0; tile < ntiles; ++tile) {
        const int s0 = tile * 32;

        __syncthreads();   // prev PV reads of KVs/Ps done (Q staged, iter 0)
        {   // ---- stage K ----
            const u16* g = kg + (size_t)(s0 + srow) * QKV_N + scol;
            u16x8 a = *(const u16x8*)g;
            u16x8 b = *(const u16x8*)(g + 8);
            #pragma unroll
            for (int e = 0; e < 8; ++e) {
                KVs[srow][scol + e]     = bf2f(a[e]);
                KVs[srow][scol + 8 + e] = bf2f(b[e]);
            }
        }
        __syncthreads();

        // ---- S = Q K^T ----
        float sv[2][2] = {{0.f, 0.f}, {0.f, 0.f}};
        for (int d = 0; d < HD; d += 4) {
            float4 k0 = *(const float4*)&KVs[tn][d];
            float4 k1 = *(const float4*)&KVs[tn + 16][d];
            float4 q0 = *(const float4*)&Qs[tm*2][d];
            float4 q1 = *(const float4*)&Qs[tm*2 + 1][d];
            sv[0][0] += q0.x*k0.x + q0.y*k0.y + q0.z*k0.z + q0.w*k0.w;
            sv[0][1] += q0.x*k1.x + q0.y*k1.y + q0.z*k1.z + q0.w*k1.w;
            sv[1][0] += q1.x*k0.x + q1.y*k0.y + q1.z*k0.z + q1.w*k0.w;
            sv[1][1] += q1.x*k1.x + q1.y*k1.y + q1.z*k1.z + q1.w*k1.w;
        }

        // ---- causal mask (diagonal tile only) ----
        if (tile == qt) {
            #pragma unroll
            for (int i = 0; i < 2; ++i) {
                const int t = t0 + tm*2 + i;
                if (s0 + tn      > t) sv[i][0] = -1.0e30f;
                if (s0 + tn + 16 > t) sv[i][1] = -1.0e30f;
            }
        }

        // ---- online softmax ----
        float mt[2] = {fmaxf(sv[0][0], sv[0][1]), fmaxf(sv[1][0], sv[1][1])};
        #pragma unroll
        for (int x = 1; x < 16; x <<= 1) {
            mt[0] = fmaxf(mt[0], __shfl_xor(mt[0], x));
            mt[1] = fmaxf(mt[1], __shfl_xor(mt[1], x));
        }
        #pragma unroll
        for (int i = 0; i < 2; ++i) {
            const float mn = fmaxf(m_run[i], mt[i]);
            const float al = __expf(m_run[i] - mn);   // 0 on first tile
            m_run[i] = mn;
            const float p0 = __expf(sv[i][0] - mn);
            const float p1 = __expf(sv[i][1] - mn);
            l_part[i] = l_part[i] * al + p0 + p1;
            #pragma unroll
            for (int k = 0; k < 8; ++k) Oa[i][k] *= al;
            Ps[tm*2 + i][tn]      = p0;
            Ps[tm*2 + i][tn + 16] = p1;
        }
        __syncthreads();   // K reads done; Ps visible

        {   // ---- stage V (overwrites KVs) ----
            const u16* g = vg + (size_t)(s0 + srow) * QKV_N + scol;
            u16x8 a = *(const u16x8*)g;
            u16x8 b = *(const u16x8*)(g + 8);
            #pragma unroll
            for (int e = 0; e < 8; ++e) {
                KVs[srow][scol + e]     = bf2f(a[e]);
                KVs[srow][scol + 8 + e] = bf2f(b[e]);
            }
        }
        __syncthreads();

        // ---- O += P V ----
        for (int j = 0; j < 32; ++j) {
            float4 v0 = *(const float4*)&KVs[j][tn*8];
            float4 v1 = *(const float4*)&KVs[j][tn*8 + 4];
            const float p0 = Ps[tm*2][j];
            const float p1 = Ps[tm*2 + 1][j];
            Oa[0][0] += p0*v0.x; Oa[0][1] += p0*v0.y;
            Oa[0][2] += p0*v0.z; Oa[0][3] += p0*v0.w;
            Oa[0][4] += p0*v1.x; Oa[0][5] += p0*v1.y;
            Oa[0][6] += p0*v1.z; Oa[0][7] += p0*v1.w;
            Oa[1][0] += p1*v0.x; Oa[1][1] += p1*v0.y;
            Oa[1][2] += p1*v0.z; Oa[1][3] += p1*v0.w;
            Oa[1][4] += p1*v1.x; Oa[1][5] += p1*v1.y;
            Oa[1][6] += p1*v1.z; Oa[1][7] += p1*v1.w;
        }
    }

    // ---- finalize ----
    #pragma unroll
    for (int x = 1; x < 16; x <<= 1) {
        l_part[0] += __shfl_xor(l_part[0], x);
        l_part[1] += __shfl_xor(l_part[1], x);
    }
    #pragma unroll
    for (int i = 0; i < 2; ++i) {
        const float inv = 1.0f / l_part[i];
        u16x8 o;
        #pragma unroll
        for (int k = 0; k < 8; ++k) o[k] = f2bf(Oa[i][k] * inv);
        *(u16x8*)(qkv + (size_t)(t0 + tm*2 + i) * QKV_N + h * HD + tn * 8) = o;
    }
}

// ---------------------------------------------------------------------------
extern "C" void kernel_launch(void* const* d_in, const int* in_sizes, int n_in,
                              void* d_out, int out_size, void* d_ws, size_t ws_size,
                              hipStream_t stream)
{
    const float* hidden    = (const float*)d_in[0];   // T x HID
    const int*   positions = (const int*)  d_in[1];   // T
    const float* qkv_w     = (const float*)d_in[2];   // 4096 x 2048
    const float* o_w       = (const float*)d_in[3];   // 2048 x 2048
    const float* q_norm_w  = (const float*)d_in[4];   // 128
    const float* k_norm_w  = (const float*)d_in[5];   // 128
    float* out = (float*)d_out;                       // T x HID (f32)

    // ws: [qkvbf 16MB][wbf 16MB][abf 8MB] = 40 MB
    u16* qkvbf = (u16*)d_ws;
    u16* wbf   = qkvbf + (size_t)T_TOK * QKV_N;
    u16* abf   = wbf   + (size_t)QKV_N * HID;

    // convert inputs to bf16
    cvt_f32_bf16<<<(T_TOK*HID)/2048, 256, 0, stream>>>(hidden, abf);
    cvt_f32_bf16<<<(QKV_N*HID)/2048, 256, 0, stream>>>(qkv_w, wbf);

    // 1) qkv(bf16) = hidden @ qkv_w^T   (MFMA)
    gemm_bt_bf16<true><<<dim3(QKV_N/128, T_TOK/128), 256, 0, stream>>>(
        abf, wbf, qkvbf, HID, HID, HID, QKV_N);

    // 2) rmsnorm + rope (in place, bf16)
    norm_rope<<<dim3(T_TOK, NH + NKV), 128, 0, stream>>>(
        qkvbf, positions, q_norm_w, k_norm_w);

    // 3) flash attention -> q slots (bf16)
    attn_flash<<<dim3(T_TOK/32, NH), 256, 0, stream>>>(qkvbf);

    // 4) out(f32) = o @ o_w^T   (MFMA); o_w bf16 reuses abf (after GEMM1)
    cvt_f32_bf16<<<(HID*HID)/2048, 256, 0, stream>>>(o_w, abf);
    gemm_bt_bf16<false><<<dim3(HID/128, T_TOK/128), 256, 0, stream>>>(
        qkvbf, abf, out, HID, QKV_N, HID, HID);
}

// Round 6
// 335.264 us; speedup vs baseline: 9.4852x; 2.8675x over previous
//
#include <hip/hip_runtime.h>
#include <math.h>

// Qwen3Attention: T=2048, HID=2048, H=16, KV=8, D=128
#define T_TOK 2048
#define HID 2048
#define NH 16
#define NKV 8
#define HD 128
#define QKV_N 4096
#define EPS 1e-6f

typedef unsigned short u16;
typedef unsigned int   u32;
typedef __attribute__((ext_vector_type(8))) u16   u16x8;
typedef __attribute__((ext_vector_type(8))) short short8;
typedef __attribute__((ext_vector_type(4))) float floatx4;
typedef __attribute__((ext_vector_type(4))) u32   u32x4;

__device__ __forceinline__ u16 f2bf(float x) {           // RNE f32->bf16
    u32 u = __float_as_uint(x);
    u = (u + 0x7fffu + ((u >> 16) & 1u)) >> 16;
    return (u16)u;
}
__device__ __forceinline__ float bf2f(u16 h) {
    return __uint_as_float(((u32)h) << 16);
}

// ---------------------------------------------------------------------------
// f32 -> bf16 elementwise (8 elems/thread). n must be a multiple of 2048.
// ---------------------------------------------------------------------------
__global__ __launch_bounds__(256) void cvt_f32_bf16(
    const float* __restrict__ in, u16* __restrict__ out)
{
    const size_t i = ((size_t)blockIdx.x * 256 + threadIdx.x) * 8;
    float4 a = *(const float4*)(in + i);
    float4 b = *(const float4*)(in + i + 4);
    u16x8 o;
    o[0] = f2bf(a.x); o[1] = f2bf(a.y); o[2] = f2bf(a.z); o[3] = f2bf(a.w);
    o[4] = f2bf(b.x); o[5] = f2bf(b.y); o[6] = f2bf(b.z); o[7] = f2bf(b.w);
    *(u16x8*)(out + i) = o;
}

// ---------------------------------------------------------------------------
// bf16 MFMA GEMM (m97 pattern): C[M,N] = A[M,K]*B[N,K]^T
// 128x128 tile, BK=32, 256 thr; global_load_lds width=16 staging.
// ---------------------------------------------------------------------------
template<bool OUT_BF16>
__global__ __launch_bounds__(256) void gemm_bt_bf16(
    const u16* __restrict__ A, const u16* __restrict__ B,
    void* __restrict__ Cv, int K, int lda, int ldb, int ldc)
{
    __shared__ short As[128 * 32];
    __shared__ short Bs[128 * 32];

    const int tid = threadIdx.x;
    const int w   = tid >> 6;
    const int l   = tid & 63;
    const int m0  = blockIdx.y * 128;
    const int n0  = blockIdx.x * 128;
    const int wm  = (w >> 1) * 64;
    const int wn  = (w & 1) * 64;
    const int lm  = l & 15;
    const int ko8 = (l >> 4) * 8;

    const u16* gA0 = A + (size_t)(m0      + (tid >> 2)) * lda + (tid & 3) * 8;
    const u16* gA1 = A + (size_t)(m0 + 64 + (tid >> 2)) * lda + (tid & 3) * 8;
    const u16* gB0 = B + (size_t)(n0      + (tid >> 2)) * ldb + (tid & 3) * 8;
    const u16* gB1 = B + (size_t)(n0 + 64 + (tid >> 2)) * ldb + (tid & 3) * 8;
    short* lA0 = As + w * 512;
    short* lA1 = As + 2048 + w * 512;
    short* lB0 = Bs + w * 512;
    short* lB1 = Bs + 2048 + w * 512;

    floatx4 acc[4][4];
    #pragma unroll
    for (int i = 0; i < 4; ++i)
        #pragma unroll
        for (int j = 0; j < 4; ++j) acc[i][j] = (floatx4){0.f, 0.f, 0.f, 0.f};

    for (int k0 = 0; k0 < K; k0 += 32) {
        __syncthreads();
        __builtin_amdgcn_global_load_lds(
            (const __attribute__((address_space(1))) u32*)(gA0 + k0),
            (__attribute__((address_space(3))) u32*)lA0, 16, 0, 0);
        __builtin_amdgcn_global_load_lds(
            (const __attribute__((address_space(1))) u32*)(gA1 + k0),
            (__attribute__((address_space(3))) u32*)lA1, 16, 0, 0);
        __builtin_amdgcn_global_load_lds(
            (const __attribute__((address_space(1))) u32*)(gB0 + k0),
            (__attribute__((address_space(3))) u32*)lB0, 16, 0, 0);
        __builtin_amdgcn_global_load_lds(
            (const __attribute__((address_space(1))) u32*)(gB1 + k0),
            (__attribute__((address_space(3))) u32*)lB1, 16, 0, 0);
        __syncthreads();

        short8 af[4], bfr[4];
        #pragma unroll
        for (int i = 0; i < 4; ++i)
            af[i] = *(const short8*)(As + (wm + i * 16 + lm) * 32 + ko8);
        #pragma unroll
        for (int j = 0; j < 4; ++j)
            bfr[j] = *(const short8*)(Bs + (wn + j * 16 + lm) * 32 + ko8);
        #pragma unroll
        for (int i = 0; i < 4; ++i)
            #pragma unroll
            for (int j = 0; j < 4; ++j)
                acc[i][j] = __builtin_amdgcn_mfma_f32_16x16x32_bf16(
                    af[i], bfr[j], acc[i][j], 0, 0, 0);
    }

    const int r0 = (l >> 4) * 4;
    #pragma unroll
    for (int i = 0; i < 4; ++i)
        #pragma unroll
        for (int j = 0; j < 4; ++j)
            #pragma unroll
            for (int r = 0; r < 4; ++r) {
                const int row = m0 + wm + i * 16 + r0 + r;
                const int col = n0 + wn + j * 16 + lm;
                if (OUT_BF16)
                    ((u16*)Cv)[(size_t)row * ldc + col] = f2bf(acc[i][j][r]);
                else
                    ((float*)Cv)[(size_t)row * ldc + col] = acc[i][j][r];
            }
}

// ---------------------------------------------------------------------------
// RMSNorm + RoPE, in-place on bf16 qkv. grid=(T, NH+NKV), 128 thr.
// ---------------------------------------------------------------------------
__global__ __launch_bounds__(128) void norm_rope(
    u16* __restrict__ qkv, const int* __restrict__ positions,
    const float* __restrict__ qw, const float* __restrict__ kw)
{
    const int t   = blockIdx.x;
    const int hh  = blockIdx.y;
    const int tid = threadIdx.x;

    u16* p; const float* w;
    if (hh < NH) { p = qkv + (size_t)t*QKV_N + hh*HD;              w = qw; }
    else         { p = qkv + (size_t)t*QKV_N + NH*HD + (hh-NH)*HD; w = kw; }

    float x = bf2f(p[tid]);

    __shared__ float red[2];
    float ss = x * x;
    #pragma unroll
    for (int o = 32; o > 0; o >>= 1) ss += __shfl_down(ss, o);
    if ((tid & 63) == 0) red[tid >> 6] = ss;
    __syncthreads();
    const float var = (red[0] + red[1]) * (1.0f / (float)HD);
    float xn = x * rsqrtf(var + EPS) * w[tid];

    __shared__ float sx[HD];
    sx[tid] = xn;
    __syncthreads();

    const int   pos = positions[t];
    const int   i   = tid & 63;
    const float inv_freq = exp2f(-(float)i * 0.311430758895690f); // log2(1e6)/64
    const float ang = (float)pos * inv_freq;
    const float s = sinf(ang);   // NOTE: sincosf ptr order trap (r1/r2 bug)
    const float c = cosf(ang);

    float out;
    if (tid < 64) out = sx[i]      * c - sx[i + 64] * s;
    else          out = sx[i + 64] * c + sx[i]      * s;
    p[tid] = f2bf(out);
}

// ---------------------------------------------------------------------------
// V transpose: vt[kv][d][t] = qkv[t][3072 + kv*128 + d]. 32x32 LDS tiles.
// grid = (T/32, HD/32, NKV), block 256.
// ---------------------------------------------------------------------------
__global__ __launch_bounds__(256) void v_transpose(
    const u16* __restrict__ qkv, u16* __restrict__ vt)
{
    const int kv = blockIdx.z;
    const int d0 = blockIdx.y * 32;
    const int t0 = blockIdx.x * 32;
    const int tid = threadIdx.x;
    __shared__ u16 tile[32][33];
    const int r  = tid >> 5;   // 0..7
    const int cc = tid & 31;
    #pragma unroll
    for (int p = 0; p < 4; ++p)
        tile[r + p*8][cc] =
            qkv[(size_t)(t0 + r + p*8)*QKV_N + (NH*HD + NKV*HD) + kv*HD + d0 + cc];
    __syncthreads();
    #pragma unroll
    for (int p = 0; p < 4; ++p)
        vt[(size_t)kv*HD*T_TOK + (size_t)(d0 + r + p*8)*T_TOK + t0 + cc] =
            tile[cc][r + p*8];
}

// ---------------------------------------------------------------------------
// MFMA flash attention (bf16 inputs, fp32 softmax/accum).
// grid = (T/64, NH), 256 thr = 4 waves. Q-tile 64 rows; wave w owns Q-cols
// [16w,16w+16). S^T = K·Q^T so query idx lands in C/D col=lane&15: softmax
// stats per-lane, no cross-wave reduction. P converted C/D->A-layout by
// register shuffles (lane&15-preserving permutation). PV B-operand from
// pre-transposed vt. Output bf16 in-place into q slots.
// ---------------------------------------------------------------------------
__global__ __launch_bounds__(256) void attn_mfma(
    u16* __restrict__ qkv, const u16* __restrict__ vt)
{
    const int qt  = (int)(gridDim.x - 1) - (int)blockIdx.x;  // heavy first
    const int h   = blockIdx.y;
    const int kvh = h >> 1;
    const int t0  = qt * 64;
    const int tid = threadIdx.x;
    const int w   = tid >> 6;
    const int l   = tid & 63;
    const int q4  = l >> 4;        // quad group 0..3
    const int c   = l & 15;        // col (query) index within 16

    __shared__ short Qs[64 * 136];   // 17408 B (pad 136 -> uniform banks)
    __shared__ short Ks[64 * 136];   // 17408 B
    __shared__ short Vts[128 * 72];  // 18432 B (rows [d][s], pad 72)

    // ---- stage Q tile (rows t0..t0+63, this head's 128 dims) ----
    {
        const int r = tid >> 2, c0 = (tid & 3) * 32;
        const u16* g = qkv + (size_t)(t0 + r)*QKV_N + h*HD + c0;
        #pragma unroll
        for (int p = 0; p < 4; ++p)
            *(u16x8*)(Qs + r*136 + c0 + p*8) = *(const u16x8*)(g + p*8);
    }

    float m_run = -3.0e38f, l_run = 0.f;
    floatx4 accO[8];
    #pragma unroll
    for (int db = 0; db < 8; ++db) accO[db] = (floatx4){0.f, 0.f, 0.f, 0.f};

    const u16* kg = qkv + NH*HD + (size_t)kvh*HD;
    const u16* vg = vt + (size_t)kvh * HD * T_TOK;

    const float Cs = 0.12751744f;   // (1/sqrt(128)) * log2(e)

    const int ntiles = qt + 1;
    for (int tile = 0; tile < ntiles; ++tile) {
        const int s0 = tile * 64;

        __syncthreads();   // prev iteration's K/Vt reads complete (Q, iter 0)
        {   // stage K tile: rows s0..s0+63
            const int r = tid >> 2, c0 = (tid & 3) * 32;
            const u16* g = kg + (size_t)(s0 + r)*QKV_N + c0;
            #pragma unroll
            for (int p = 0; p < 4; ++p)
                *(u16x8*)(Ks + r*136 + c0 + p*8) = *(const u16x8*)(g + p*8);
        }
        {   // stage Vt tile: rows d=0..127, cols s0..s0+63
            const int d = tid >> 1, c0 = (tid & 1) * 32;
            const u16* g = vg + (size_t)d * T_TOK + s0 + c0;
            #pragma unroll
            for (int p = 0; p < 4; ++p)
                *(u16x8*)(Vts + d*72 + c0 + p*8) = *(const u16x8*)(g + p*8);
        }
        __syncthreads();

        // ---- S^T = K Q^T : accS[sb] covers s rows [16sb,16sb+16), q cols 16w+c
        floatx4 accS[4];
        #pragma unroll
        for (int sb = 0; sb < 4; ++sb) accS[sb] = (floatx4){0.f, 0.f, 0.f, 0.f};
        #pragma unroll
        for (int kk = 0; kk < 4; ++kk) {
            short8 bq = *(const short8*)(Qs + (w*16 + c)*136 + kk*32 + q4*8);
            #pragma unroll
            for (int sb = 0; sb < 4; ++sb) {
                short8 ak = *(const short8*)(Ks + (sb*16 + c)*136 + kk*32 + q4*8);
                accS[sb] = __builtin_amdgcn_mfma_f32_16x16x32_bf16(ak, bq, accS[sb], 0, 0, 0);
            }
        }

        // ---- causal mask on diagonal tile (s0 == t0 there) ----
        if (tile == qt) {
            #pragma unroll
            for (int sb = 0; sb < 4; ++sb)
                #pragma unroll
                for (int r = 0; r < 4; ++r) {
                    const int s_loc = sb*16 + q4*4 + r;
                    const int t_loc = w*16 + c;
                    if (s_loc > t_loc) accS[sb][r] = -1.0e30f;
                }
        }

        // ---- online softmax (per query col c; quads deduplicated by xor) ----
        float mt = -3.0e38f;
        #pragma unroll
        for (int sb = 0; sb < 4; ++sb)
            #pragma unroll
            for (int r = 0; r < 4; ++r) mt = fmaxf(mt, accS[sb][r]);
        mt = fmaxf(mt, __shfl_xor(mt, 16));
        mt = fmaxf(mt, __shfl_xor(mt, 32));

        const float m_new = fmaxf(m_run, mt);
        const float alpha = exp2f((m_run - m_new) * Cs);  // 0 on first tile
        m_run = m_new;

        float P[4][4];
        float lsum = 0.f;
        #pragma unroll
        for (int sb = 0; sb < 4; ++sb)
            #pragma unroll
            for (int r = 0; r < 4; ++r) {
                const float e = exp2f((accS[sb][r] - m_new) * Cs);
                P[sb][r] = e;
                lsum += e;
            }
        lsum += __shfl_xor(lsum, 16);
        lsum += __shfl_xor(lsum, 32);
        l_run = l_run * alpha + lsum;

        // ---- rescale O by alpha (alpha lives per col c; O rows are 4q+r) ----
        #pragma unroll
        for (int r = 0; r < 4; ++r) {
            const float ar = __shfl(alpha, (l & 48) | (q4*4 + r));
            #pragma unroll
            for (int db = 0; db < 8; ++db) accO[db][r] *= ar;
        }

        // ---- pack P to bf16 pairs: Pp[sb][p] = (r=2p lo, r=2p+1 hi) ----
        u32 Pp[4][2];
        #pragma unroll
        for (int sb = 0; sb < 4; ++sb)
            #pragma unroll
            for (int p = 0; p < 2; ++p)
                Pp[sb][p] = (u32)f2bf(P[sb][2*p]) | ((u32)f2bf(P[sb][2*p+1]) << 16);

        // ---- PV: O[m][d] += P[m][s] * Vt[d][s] ----
        const int src0 = ((2*q4    ) & 3) * 16 + c;
        const int src1 = ((2*q4 + 1) & 3) * 16 + c;
        const bool hiq = q4 >= 2;
        #pragma unroll
        for (int k2 = 0; k2 < 2; ++k2) {
            // A-frag of P for s in [32*k2, 32*k2+32): lane needs
            // P[m=c][s = 32*k2 + 8*q4 + j], j=0..7 (verified lane-level)
            u32 x0 = __shfl(Pp[2*k2][0],   src0), y0 = __shfl(Pp[2*k2+1][0], src0);
            u32 x1 = __shfl(Pp[2*k2][1],   src0), y1 = __shfl(Pp[2*k2+1][1], src0);
            u32 x2 = __shfl(Pp[2*k2][0],   src1), y2 = __shfl(Pp[2*k2+1][0], src1);
            u32 x3 = __shfl(Pp[2*k2][1],   src1), y3 = __shfl(Pp[2*k2+1][1], src1);
            u32x4 av;
            av.x = hiq ? y0 : x0;  av.y = hiq ? y1 : x1;
            av.z = hiq ? y2 : x2;  av.w = hiq ? y3 : x3;
            const short8 aP = __builtin_bit_cast(short8, av);
            #pragma unroll
            for (int db = 0; db < 8; ++db) {
                short8 bv = *(const short8*)(Vts + (db*16 + c)*72 + k2*32 + q4*8);
                accO[db] = __builtin_amdgcn_mfma_f32_16x16x32_bf16(aP, bv, accO[db], 0, 0, 0);
            }
        }
    }

    // ---- finalize: O /= l (l lives per col c; O rows are 4q+r) ----
    const float inv = 1.0f / l_run;
    #pragma unroll
    for (int r = 0; r < 4; ++r) {
        const float ir = __shfl(inv, (l & 48) | (q4*4 + r));
        const int row_g = t0 + w*16 + q4*4 + r;
        u16* op = qkv + (size_t)row_g * QKV_N + h*HD;
        #pragma unroll
        for (int db = 0; db < 8; ++db)
            op[db*16 + c] = f2bf(accO[db][r] * ir);
    }
}

// ---------------------------------------------------------------------------
extern "C" void kernel_launch(void* const* d_in, const int* in_sizes, int n_in,
                              void* d_out, int out_size, void* d_ws, size_t ws_size,
                              hipStream_t stream)
{
    const float* hidden    = (const float*)d_in[0];   // T x HID
    const int*   positions = (const int*)  d_in[1];   // T
    const float* qkv_w     = (const float*)d_in[2];   // 4096 x 2048
    const float* o_w       = (const float*)d_in[3];   // 2048 x 2048
    const float* q_norm_w  = (const float*)d_in[4];   // 128
    const float* k_norm_w  = (const float*)d_in[5];   // 128
    float* out = (float*)d_out;                       // T x HID (f32)

    // ws: [qkvbf 16MB][wbf 16MB][abf 8MB][vt 4MB] = 44 MB
    u16* qkvbf = (u16*)d_ws;
    u16* wbf   = qkvbf + (size_t)T_TOK * QKV_N;
    u16* abf   = wbf   + (size_t)QKV_N * HID;
    u16* vtb   = abf   + (size_t)T_TOK * HID;

    cvt_f32_bf16<<<(T_TOK*HID)/2048, 256, 0, stream>>>(hidden, abf);
    cvt_f32_bf16<<<(QKV_N*HID)/2048, 256, 0, stream>>>(qkv_w, wbf);

    // 1) qkv(bf16) = hidden @ qkv_w^T
    gemm_bt_bf16<true><<<dim3(QKV_N/128, T_TOK/128), 256, 0, stream>>>(
        abf, wbf, qkvbf, HID, HID, HID, QKV_N);

    // 2) rmsnorm + rope on q,k
    norm_rope<<<dim3(T_TOK, NH + NKV), 128, 0, stream>>>(
        qkvbf, positions, q_norm_w, k_norm_w);

    // 2b) vt[kv][d][t] = V^T (V untouched by norm/rope)
    v_transpose<<<dim3(T_TOK/32, HD/32, NKV), 256, 0, stream>>>(qkvbf, vtb);

    // 3) MFMA flash attention -> q slots (bf16)
    attn_mfma<<<dim3(T_TOK/64, NH), 256, 0, stream>>>(qkvbf, vtb);

    // 4) out(f32) = o @ o_w^T  (o_w bf16 reuses abf)
    cvt_f32_bf16<<<(HID*HID)/2048, 256, 0, stream>>>(o_w, abf);
    gemm_bt_bf16<false><<<dim3(HID/128, T_TOK/128), 256, 0, stream>>>(
        qkvbf, abf, out, HID, QKV_N, HID, HID);
}